// Round 7
// baseline (80.084 us; speedup 1.0000x reference)
//
#include <hip/hip_runtime.h>
#include <math.h>

#define EPSF 1e-7f

typedef __attribute__((ext_vector_type(4))) float f32x4;
typedef __attribute__((ext_vector_type(8))) short s16x8;

__device__ __forceinline__ unsigned short f2bf(float f) {
    unsigned u = __float_as_uint(f);
    u = (u + 0x7fffu + ((u >> 16) & 1u)) >> 16;
    return (unsigned short)u;
}
__device__ __forceinline__ float bf2f(unsigned short s) {
    return __uint_as_float(((unsigned)s) << 16);
}
__device__ __forceinline__ float wave_reduce_sum(float v) {
    #pragma unroll
    for (int o = 32; o > 0; o >>= 1) v += __shfl_xor(v, o, 64);
    return v;
}

// K0: prep pass. blocks 0..191: W_qkv f32[512][1536] -> WqT bf16[1536][512];
// blocks 192..255: W_out f32[512][512] -> WoT bf16[512][512];
// blocks 256..263: x norms -> sL (logmap row scale) + x -> bf16.
__global__ __launch_bounds__(256, 4) void k_prep(
        const float* __restrict__ W_qkv, const float* __restrict__ W_out,
        const float* __restrict__ x, const float* __restrict__ c_sphere,
        unsigned short* __restrict__ WqT, unsigned short* __restrict__ WoT,
        unsigned short* __restrict__ x16, float* __restrict__ sL_g) {
    int b = blockIdx.x;
    int tid = threadIdx.x;
    if (b < 256) {
        const float* in; unsigned short* out; int N, bx, by;
        if (b < 192) { in = W_qkv; out = WqT; N = 1536; bx = b % 24; by = b / 24; }
        else { int b2 = b - 192; in = W_out; out = WoT; N = 512; bx = b2 % 8; by = b2 / 8; }
        const int K = 512;
        __shared__ float t[64][65];
        int k0 = by * 64, n0 = bx * 64;
        int c = tid & 63, r0 = tid >> 6;
        #pragma unroll
        for (int i = 0; i < 16; ++i) {
            int r = i * 4 + r0;
            t[r][c] = in[(size_t)(k0 + r) * N + n0 + c];
        }
        __syncthreads();
        #pragma unroll
        for (int i = 0; i < 16; ++i) {
            int r = i * 4 + r0;
            out[(size_t)(n0 + r) * K + k0 + c] = f2bf(t[c][r]);
        }
    } else {
        int row0 = (b - 256) * 64;
        __shared__ float part[64][4];
        int row_l = tid >> 2, seg = tid & 3;
        const float* xr = x + (size_t)(row0 + row_l) * 512 + seg * 128;
        float ss = 0.f;
        #pragma unroll
        for (int i = 0; i < 32; ++i) {
            float4 v = *(const float4*)(xr + i * 4);
            ss += v.x * v.x + v.y * v.y + v.z * v.z + v.w * v.w;
        }
        part[row_l][seg] = ss;
        __syncthreads();
        if (tid < 64) {
            float s2 = part[tid][0] + part[tid][1] + part[tid][2] + part[tid][3];
            float c = c_sphere[0];
            float sqc = fmaxf(sqrtf(c), EPSF);
            float yn = sqrtf(s2);
            sL_g[row0 + tid] = (yn < EPSF) ? 0.f
                : atanhf(fminf(yn, 1.f - EPSF)) / (sqc * fmaxf(yn, EPSF));
        }
        // cvt x rows [row0, row0+64) to bf16, vectorized
        for (int idx = tid; idx < 64 * 128; idx += 256) {
            int r = idx >> 7, c4 = (idx & 127) * 4;
            float4 v = *(const float4*)(x + (size_t)(row0 + r) * 512 + c4);
            ushort4 o = make_ushort4(f2bf(v.x), f2bf(v.y), f2bf(v.z), f2bf(v.w));
            *(ushort4*)(x16 + (size_t)(row0 + r) * 512 + c4) = o;
        }
    }
}

// K1: fused QKV GEMM + RoPE + expmap0.
// Block: 32 rows x 128 cols of qkv. GEMM (all-bf16 MFMA, contiguous frags) ->
// scale(sL)+bias -> LDS patch [32][129] -> per-region RoPE/expmap/relayout.
// 128-col patches align with 64-col head spans, so each head is fully local.
__global__ __launch_bounds__(256, 2) void k_qkv_rope(
        const unsigned short* __restrict__ x16, const unsigned short* __restrict__ WqT,
        const float* __restrict__ bias, const float* __restrict__ sL_g,
        const float* __restrict__ freqs, const float* __restrict__ c_logits,
        unsigned short* __restrict__ qh, unsigned short* __restrict__ kh,
        unsigned short* __restrict__ vt,
        float* __restrict__ x2q, float* __restrict__ y2k) {
    const int K = 512, N = 512;
    int b = blockIdx.x;
    int wr = b / 12, cgrp = b % 12;
    int c0 = cgrp * 128;
    int tid = threadIdx.x, wv = tid >> 6, lane = tid & 63;
    int l15 = lane & 15, kb = lane >> 4;
    int col0 = c0 + wv * 32;
    __shared__ float patch[32][129];   // stride 129 -> conflict-free kb groups
    const unsigned short* Ab = x16 + (size_t)(wr * 32 + l15) * K + kb * 8;
    const unsigned short* Bb = WqT + (size_t)(col0 + l15) * K + kb * 8;
    f32x4 acc[2][2] = {};
    #pragma unroll 4
    for (int k0 = 0; k0 < K; k0 += 32) {
        s16x8 a0 = *(const s16x8*)(Ab + k0);
        s16x8 a1 = *(const s16x8*)(Ab + 16 * K + k0);
        s16x8 b0 = *(const s16x8*)(Bb + k0);
        s16x8 b1 = *(const s16x8*)(Bb + 16 * K + k0);
        acc[0][0] = __builtin_amdgcn_mfma_f32_16x16x32_bf16(a0, b0, acc[0][0], 0, 0, 0);
        acc[0][1] = __builtin_amdgcn_mfma_f32_16x16x32_bf16(a0, b1, acc[0][1], 0, 0, 0);
        acc[1][0] = __builtin_amdgcn_mfma_f32_16x16x32_bf16(a1, b0, acc[1][0], 0, 0, 0);
        acc[1][1] = __builtin_amdgcn_mfma_f32_16x16x32_bf16(a1, b1, acc[1][1], 0, 0, 0);
    }
    #pragma unroll
    for (int mi = 0; mi < 2; ++mi)
        #pragma unroll
        for (int r = 0; r < 4; ++r) {
            int row_l = mi * 16 + kb * 4 + r;
            float sc = sL_g[wr * 32 + row_l];
            #pragma unroll
            for (int ni = 0; ni < 2; ++ni) {
                int col = col0 + ni * 16 + l15;
                patch[row_l][wv * 32 + ni * 16 + l15] = acc[mi][ni][r] * sc + bias[col];
            }
        }
    __syncthreads();
    if (c0 < 1024) {
        // q or k region: RoPE + expmap per (row, head) pair; 64 pairs, wave wv
        // takes pairs p = wv + 4*it. Lane j handles head-col j.
        bool isq = (c0 < 512);
        int h0 = (isq ? c0 : c0 - 512) >> 6;
        int j = lane;
        #pragma unroll 4
        for (int it = 0; it < 16; ++it) {
            int p = wv + 4 * it;
            int row_l = p >> 1, head_l = p & 1;
            int n = wr * 32 + row_l;
            int h = h0 + head_l;
            float c = log1pf(expf(c_logits[h]));
            float sqc = fmaxf(sqrtf(c), EPSF);
            float val = patch[row_l][head_l * 64 + j];
            float other = __shfl_xor(val, 32, 64);
            float f = freqs[n * 32 + (j & 31)];
            float cs = cosf(f), sn = sinf(f);
            float qr = (j < 32) ? (val * cs - other * sn) : (other * sn + val * cs);
            float vn2 = wave_reduce_sum(qr * qr);
            float vn = sqrtf(vn2);
            float scale, fn;
            if (vn < EPSF) { scale = 0.f; fn = 0.f; }
            else {
                float mag = tanhf(sqc * vn) / sqc;
                scale = mag / fmaxf(vn, EPSF);
                fn = mag;
                if (fn >= 1.f) { scale *= (1.f - EPSF) / fn; fn = 1.f - EPSF; }
            }
            size_t oidx = ((size_t)h * N + n) * 64 + j;
            if (isq) {
                qh[oidx] = f2bf(qr * scale);
                if (j == 0) x2q[h * N + n] = fn * fn;
            } else {
                kh[oidx] = f2bf(qr * scale);
                if (j == 0) y2k[h * N + n] = fn * fn;
            }
        }
    } else {
        // v region: cvt + transposed store vt[h][d][n]
        int h0 = (c0 - 1024) >> 6;
        for (int idx = tid; idx < 32 * 128; idx += 256) {
            int row_l = idx >> 7, cl = idx & 127;
            int h = h0 + (cl >> 6), d = cl & 63;
            int n = wr * 32 + row_l;
            vt[((size_t)(h * 64 + d)) * N + n] = f2bf(patch[row_l][cl]);
        }
    }
}

// K2: QK^T via MFMA per lower-triangular (h, 64x64 tile); epilogue computes
// hyperbolic dist + causal mask + exp -> P(bf16).
__global__ __launch_bounds__(256, 4) void k_qkt_mfma(
        const unsigned short* __restrict__ qh, const unsigned short* __restrict__ kh,
        const float* __restrict__ x2q, const float* __restrict__ y2k,
        const float* __restrict__ c_logits, const float* __restrict__ geo_scale,
        unsigned short* __restrict__ P) {
    const int N = 512;
    int p = blockIdx.x, h = blockIdx.y;
    int qt = 0;
    while ((qt + 1) * (qt + 2) / 2 <= p) qt++;
    int kt = p - qt * (qt + 1) / 2;
    int tid = threadIdx.x, lane = tid & 63, wv = tid >> 6;
    int wr = wv >> 1, wc = wv & 1;
    int l15 = lane & 15, kb = lane >> 4;
    int qrow0 = qt * 64 + wr * 32, kcol0 = kt * 64 + wc * 32;
    const unsigned short* qb = qh + ((size_t)h * N + qrow0 + l15) * 64 + kb * 8;
    const unsigned short* kb_ = kh + ((size_t)h * N + kcol0 + l15) * 64 + kb * 8;
    f32x4 acc[2][2] = {};
    #pragma unroll
    for (int kk = 0; kk < 2; ++kk) {
        s16x8 a0 = *(const s16x8*)(qb + kk * 32);
        s16x8 a1 = *(const s16x8*)(qb + 16 * 64 + kk * 32);
        s16x8 b0 = *(const s16x8*)(kb_ + kk * 32);
        s16x8 b1 = *(const s16x8*)(kb_ + 16 * 64 + kk * 32);
        acc[0][0] = __builtin_amdgcn_mfma_f32_16x16x32_bf16(a0, b0, acc[0][0], 0, 0, 0);
        acc[0][1] = __builtin_amdgcn_mfma_f32_16x16x32_bf16(a0, b1, acc[0][1], 0, 0, 0);
        acc[1][0] = __builtin_amdgcn_mfma_f32_16x16x32_bf16(a1, b0, acc[1][0], 0, 0, 0);
        acc[1][1] = __builtin_amdgcn_mfma_f32_16x16x32_bf16(a1, b1, acc[1][1], 0, 0, 0);
    }
    float c = log1pf(expf(c_logits[h]));
    float sqc = fmaxf(sqrtf(c), EPSF);
    float gs = geo_scale[h];
    #pragma unroll
    for (int mi = 0; mi < 2; ++mi)
        #pragma unroll
        for (int r = 0; r < 4; ++r) {
            int qi = qrow0 + mi * 16 + kb * 4 + r;
            float x2 = x2q[h * N + qi];
            float b_ = 1.f - c * x2;
            #pragma unroll
            for (int ni = 0; ni < 2; ++ni) {
                int ki = kcol0 + ni * 16 + l15;
                float y2 = y2k[h * N + ki];
                float dot = acc[mi][ni][r];
                float a_ = 1.f + c * (y2 - 2.f * dot);
                float num2 = a_ * a_ * x2 + b_ * b_ * y2 - 2.f * a_ * b_ * dot;
                float den = fmaxf(1.f - 2.f * c * dot + c * c * x2 * y2, EPSF);
                float nrm = sqrtf(fmaxf(num2, 0.f)) / den;
                if (nrm >= 1.f) nrm = 1.f - EPSF;
                float arg = fminf(sqc * nrm, 1.f - EPSF);
                float s = -gs * (2.f * atanhf(arg) / sqc);
                float pe = (ki <= qi) ? expf(s) : 0.f;
                P[((size_t)(h * N + qi)) * N + ki] = f2bf(pe);
            }
        }
}

// K3: O = P @ V via MFMA with fused row-sum (P zero above diagonal makes the
// full fragment sum the exact softmax denominator).
__global__ __launch_bounds__(256, 4) void k_pv_mfma(
        const unsigned short* __restrict__ P, const unsigned short* __restrict__ vt,
        unsigned short* __restrict__ aout) {
    const int N = 512;
    int qt = blockIdx.x, h = blockIdx.y;
    int tid = threadIdx.x, lane = tid & 63, wv = tid >> 6;
    int wr = wv >> 1, wc = wv & 1;
    int l15 = lane & 15, kb = lane >> 4;
    int r0 = qt * 64 + wr * 32;
    int d0 = wc * 32;
    __shared__ float sums[64];
    const unsigned short* Pb = P + ((size_t)(h * N + r0 + l15)) * N + kb * 8;
    const unsigned short* Vb = vt + ((size_t)(h * 64 + d0 + l15)) * N + kb * 8;
    f32x4 acc[2][2] = {};
    float sa0 = 0.f, sa1 = 0.f;
    int kend = r0 + 32;
    for (int k0 = 0; k0 < kend; k0 += 32) {
        s16x8 a0 = *(const s16x8*)(Pb + k0);
        s16x8 a1 = *(const s16x8*)(Pb + (size_t)16 * N + k0);
        s16x8 b0 = *(const s16x8*)(Vb + k0);
        s16x8 b1 = *(const s16x8*)(Vb + (size_t)16 * N + k0);
        #pragma unroll
        for (int t = 0; t < 8; ++t) {
            sa0 += bf2f((unsigned short)a0[t]);
            sa1 += bf2f((unsigned short)a1[t]);
        }
        acc[0][0] = __builtin_amdgcn_mfma_f32_16x16x32_bf16(a0, b0, acc[0][0], 0, 0, 0);
        acc[0][1] = __builtin_amdgcn_mfma_f32_16x16x32_bf16(a0, b1, acc[0][1], 0, 0, 0);
        acc[1][0] = __builtin_amdgcn_mfma_f32_16x16x32_bf16(a1, b0, acc[1][0], 0, 0, 0);
        acc[1][1] = __builtin_amdgcn_mfma_f32_16x16x32_bf16(a1, b1, acc[1][1], 0, 0, 0);
    }
    sa0 += __shfl_xor(sa0, 16, 64); sa0 += __shfl_xor(sa0, 32, 64);
    sa1 += __shfl_xor(sa1, 16, 64); sa1 += __shfl_xor(sa1, 32, 64);
    if (wc == 0 && kb == 0) {
        sums[wr * 32 + l15] = sa0;
        sums[wr * 32 + 16 + l15] = sa1;
    }
    __syncthreads();
    #pragma unroll
    for (int mi = 0; mi < 2; ++mi)
        #pragma unroll
        for (int r = 0; r < 4; ++r) {
            int row_l = wr * 32 + mi * 16 + kb * 4 + r;
            int qi = qt * 64 + row_l;
            float il = 1.f / sums[row_l];
            #pragma unroll
            for (int ni = 0; ni < 2; ++ni) {
                int d = d0 + ni * 16 + l15;
                aout[(size_t)qi * 512 + h * 64 + d] = f2bf(acc[mi][ni][r] * il);
            }
        }
}

// K4: out = aout(bf16) @ WoT(bf16)^T + b. Clean contiguous fragments.
__global__ __launch_bounds__(256, 4) void k_out(
        const unsigned short* __restrict__ A, const unsigned short* __restrict__ Bt,
        const float* __restrict__ bias, float* __restrict__ C) {
    const int K = 512, NN = 512;
    int tid = threadIdx.x;
    int wv = tid >> 6, lane = tid & 63, l15 = lane & 15, kb = lane >> 4;
    int wid = blockIdx.x * 4 + wv;
    int wr = wid / 16, wc = wid % 16;
    int col0 = wc * 32;
    const unsigned short* Ab = A + (size_t)(wr * 32 + l15) * K + kb * 8;
    const unsigned short* Bb = Bt + (size_t)(col0 + l15) * K + kb * 8;
    f32x4 acc[2][2] = {};
    #pragma unroll 4
    for (int k0 = 0; k0 < K; k0 += 32) {
        s16x8 a0 = *(const s16x8*)(Ab + k0);
        s16x8 a1 = *(const s16x8*)(Ab + 16 * K + k0);
        s16x8 b0 = *(const s16x8*)(Bb + k0);
        s16x8 b1 = *(const s16x8*)(Bb + 16 * K + k0);
        acc[0][0] = __builtin_amdgcn_mfma_f32_16x16x32_bf16(a0, b0, acc[0][0], 0, 0, 0);
        acc[0][1] = __builtin_amdgcn_mfma_f32_16x16x32_bf16(a0, b1, acc[0][1], 0, 0, 0);
        acc[1][0] = __builtin_amdgcn_mfma_f32_16x16x32_bf16(a1, b0, acc[1][0], 0, 0, 0);
        acc[1][1] = __builtin_amdgcn_mfma_f32_16x16x32_bf16(a1, b1, acc[1][1], 0, 0, 0);
    }
    #pragma unroll
    for (int mi = 0; mi < 2; ++mi)
        #pragma unroll
        for (int r = 0; r < 4; ++r) {
            int row = wr * 32 + mi * 16 + kb * 4 + r;
            #pragma unroll
            for (int ni = 0; ni < 2; ++ni) {
                int col = col0 + ni * 16 + l15;
                C[(size_t)row * NN + col] = acc[mi][ni][r] + bias[col];
            }
        }
}

extern "C" void kernel_launch(void* const* d_in, const int* in_sizes, int n_in,
                              void* d_out, int out_size, void* d_ws, size_t ws_size,
                              hipStream_t stream) {
    const float* x_hyp     = (const float*)d_in[0];
    const float* freqs     = (const float*)d_in[1];
    const float* c_sphere  = (const float*)d_in[2];
    const float* w_qkv     = (const float*)d_in[3];
    const float* b_qkv     = (const float*)d_in[4];
    const float* w_out     = (const float*)d_in[5];
    const float* b_out     = (const float*)d_in[6];
    const float* c_logits  = (const float*)d_in[7];
    const float* geo_scale = (const float*)d_in[8];
    float* out = (float*)d_out;

    const int N = 512, H = 8;
    char* base = (char*)d_ws;
    unsigned short* WqT    = (unsigned short*)base;    base += 1536 * 512 * 2;
    unsigned short* WoT    = (unsigned short*)base;    base += 512 * 512 * 2;
    unsigned short* x16    = (unsigned short*)base;    base += 512 * 512 * 2;
    float*          sL_g   = (float*)base;             base += 4 * 1024;
    unsigned short* qh16   = (unsigned short*)base;    base += 512 * 1024;
    unsigned short* kh16   = (unsigned short*)base;    base += 512 * 1024;
    unsigned short* vt16   = (unsigned short*)base;    base += 512 * 1024;
    unsigned short* aout16 = (unsigned short*)base;    base += 512 * 1024;
    float*          x2q    = (float*)base;             base += 16 * 1024;
    float*          y2k    = (float*)base;             base += 16 * 1024;
    unsigned short* P16    = (unsigned short*)base;    base += 4 * 1024 * 1024;

    k_prep<<<264, 256, 0, stream>>>(w_qkv, w_out, x_hyp, c_sphere, WqT, WoT, x16, sL_g);
    k_qkv_rope<<<192, 256, 0, stream>>>(x16, WqT, b_qkv, sL_g, freqs, c_logits,
                                        qh16, kh16, vt16, x2q, y2k);
    k_qkt_mfma<<<dim3(36, H), 256, 0, stream>>>(qh16, kh16, x2q, y2k,
                                                c_logits, geo_scale, P16);
    k_pv_mfma<<<dim3(8, H), 256, 0, stream>>>(P16, vt16, aout16);
    k_out<<<64, 256, 0, stream>>>(aout16, WoT, b_out, out);
}

// Round 8
// 78.177 us; speedup vs baseline: 1.0244x; 1.0244x over previous
//
#include <hip/hip_runtime.h>
#include <math.h>

#define EPSF 1e-7f

typedef __attribute__((ext_vector_type(4))) float f32x4;
typedef __attribute__((ext_vector_type(8))) short s16x8;

__device__ __forceinline__ unsigned short f2bf(float f) {
    unsigned u = __float_as_uint(f);
    u = (u + 0x7fffu + ((u >> 16) & 1u)) >> 16;
    return (unsigned short)u;
}
__device__ __forceinline__ float bf2f(unsigned short s) {
    return __uint_as_float(((unsigned)s) << 16);
}
// HW packed f32->bf16 (RNE), 2 elements per instruction.
__device__ __forceinline__ unsigned cvt_pk_bf16(float lo, float hi) {
    unsigned r;
    asm("v_cvt_pk_bf16_f32 %0, %1, %2" : "=v"(r) : "v"(lo), "v"(hi));
    return r;
}
__device__ __forceinline__ s16x8 cvt8pk(const float* p) {
    float4 v0 = *(const float4*)(p);
    float4 v1 = *(const float4*)(p + 4);
    union { unsigned u[4]; s16x8 v; } r;
    r.u[0] = cvt_pk_bf16(v0.x, v0.y);
    r.u[1] = cvt_pk_bf16(v0.z, v0.w);
    r.u[2] = cvt_pk_bf16(v1.x, v1.y);
    r.u[3] = cvt_pk_bf16(v1.z, v1.w);
    return r.v;
}
__device__ __forceinline__ s16x8 pack8(const float* w) {
    union { unsigned u[4]; s16x8 v; } r;
    #pragma unroll
    for (int i = 0; i < 4; ++i) r.u[i] = cvt_pk_bf16(w[2 * i], w[2 * i + 1]);
    return r.v;
}
__device__ __forceinline__ float wave_reduce_sum(float v) {
    #pragma unroll
    for (int o = 32; o > 0; o >>= 1) v += __shfl_xor(v, o, 64);
    return v;
}

// K1: qkv = diag(s_logmap) * (x @ W_qkv) + b. A = x fp32 cvt in-reg (HW pk),
// B = W fp32 [K][N] strided-gathered + pk-cvt. Row-scale via LDS prologue.
__global__ __launch_bounds__(256, 4) void k_qkv(
        const float* __restrict__ x, const float* __restrict__ W,
        const float* __restrict__ bias, const float* __restrict__ c_sphere,
        float* __restrict__ qkv) {
    const int K = 512, NN = 1536;
    __shared__ float part[32][8];
    __shared__ float sL[32];
    int tid = threadIdx.x;
    int wid0 = blockIdx.x * 4;
    int wr = wid0 / 48;                       // same for all 4 waves
    {   // prologue: ||x_row||^2 for the block's 32 rows
        int row = tid >> 3, seg = tid & 7;
        const float* xr = x + (size_t)(wr * 32 + row) * K + seg * 64;
        float ss = 0.f;
        #pragma unroll
        for (int i = 0; i < 16; ++i) {
            float4 v = *(const float4*)(xr + i * 4);
            ss += v.x * v.x + v.y * v.y + v.z * v.z + v.w * v.w;
        }
        part[row][seg] = ss;
    }
    __syncthreads();
    if (tid < 32) {
        float ss = 0.f;
        #pragma unroll
        for (int i = 0; i < 8; ++i) ss += part[tid][i];
        float c = c_sphere[0];
        float sqc = fmaxf(sqrtf(c), EPSF);
        float yn = sqrtf(ss);
        sL[tid] = (yn < EPSF) ? 0.f
                 : atanhf(fminf(yn, 1.f - EPSF)) / (sqc * fmaxf(yn, EPSF));
    }
    __syncthreads();
    int wv = tid >> 6, lane = tid & 63, l15 = lane & 15, kb = lane >> 4;
    int wc = (wid0 + wv) % 48;
    int col0 = wc * 32;
    const float* Ab = x + (size_t)(wr * 32 + l15) * K + kb * 8;
    f32x4 acc[2][2] = {};
    #pragma unroll 2
    for (int k0 = 0; k0 < K; k0 += 32) {
        s16x8 a0 = cvt8pk(Ab + k0);
        s16x8 a1 = cvt8pk(Ab + 16 * K + k0);
        float w0[8], w1[8];
        #pragma unroll
        for (int t = 0; t < 8; ++t) {
            const float* wp = W + (size_t)(k0 + kb * 8 + t) * NN + col0 + l15;
            w0[t] = wp[0];
            w1[t] = wp[16];
        }
        s16x8 b0 = pack8(w0);
        s16x8 b1 = pack8(w1);
        acc[0][0] = __builtin_amdgcn_mfma_f32_16x16x32_bf16(a0, b0, acc[0][0], 0, 0, 0);
        acc[0][1] = __builtin_amdgcn_mfma_f32_16x16x32_bf16(a0, b1, acc[0][1], 0, 0, 0);
        acc[1][0] = __builtin_amdgcn_mfma_f32_16x16x32_bf16(a1, b0, acc[1][0], 0, 0, 0);
        acc[1][1] = __builtin_amdgcn_mfma_f32_16x16x32_bf16(a1, b1, acc[1][1], 0, 0, 0);
    }
    #pragma unroll
    for (int mi = 0; mi < 2; ++mi)
        #pragma unroll
        for (int r = 0; r < 4; ++r) {
            int row_l = mi * 16 + kb * 4 + r;
            int row = wr * 32 + row_l;
            float sc = sL[row_l];
            #pragma unroll
            for (int ni = 0; ni < 2; ++ni) {
                int col = col0 + ni * 16 + l15;
                qkv[(size_t)row * NN + col] = acc[mi][ni][r] * sc + bias[col];
            }
        }
}

// K2: RoPE on q,k; expmap0; relayouts. One wave per (h,n) vector.
__global__ void k_rope_expmap(const float* __restrict__ qkv, const float* __restrict__ freqs,
                              const float* __restrict__ c_logits,
                              unsigned short* __restrict__ qh, unsigned short* __restrict__ kh,
                              unsigned short* __restrict__ vt,
                              float* __restrict__ x2q, float* __restrict__ y2k) {
    const int N = 512;
    int wave = threadIdx.x >> 6, lane = threadIdx.x & 63;
    int vec = blockIdx.x * 4 + wave;     // vec = h*N + n
    int h = vec >> 9;
    int n = vec & 511;
    float c = log1pf(expf(c_logits[h]));
    float sqc = fmaxf(sqrtf(c), EPSF);
    int j = lane & 31;
    float f = freqs[n * 32 + j];
    float cs = cosf(f), sn = sinf(f);
    const float* base = qkv + (size_t)n * 1536;
    size_t oidx = ((size_t)h * N + n) * 64 + lane;
    {
        float qa = base[h * 64 + lane];
        float qb = base[h * 64 + (lane ^ 32)];
        float qr = (lane < 32) ? (qa * cs - qb * sn) : (qa * cs + qb * sn);
        float vn2 = wave_reduce_sum(qr * qr);
        float vn = sqrtf(vn2);
        float scale, fn;
        if (vn < EPSF) { scale = 0.f; fn = 0.f; }
        else {
            float mag = tanhf(sqc * vn) / sqc;
            scale = mag / fmaxf(vn, EPSF);
            fn = mag;
            if (fn >= 1.f) { scale *= (1.f - EPSF) / fn; fn = 1.f - EPSF; }
        }
        qh[oidx] = f2bf(qr * scale);
        if (lane == 0) x2q[h * N + n] = fn * fn;
    }
    {
        float ka = base[512 + h * 64 + lane];
        float kb = base[512 + h * 64 + (lane ^ 32)];
        float kr = (lane < 32) ? (ka * cs - kb * sn) : (ka * cs + kb * sn);
        float vn2 = wave_reduce_sum(kr * kr);
        float vn = sqrtf(vn2);
        float scale, fn;
        if (vn < EPSF) { scale = 0.f; fn = 0.f; }
        else {
            float mag = tanhf(sqc * vn) / sqc;
            scale = mag / fmaxf(vn, EPSF);
            fn = mag;
            if (fn >= 1.f) { scale *= (1.f - EPSF) / fn; fn = 1.f - EPSF; }
        }
        kh[oidx] = f2bf(kr * scale);
        if (lane == 0) y2k[h * N + n] = fn * fn;
    }
    vt[((size_t)h * 64 + lane) * N + n] = f2bf(base[1024 + h * 64 + lane]);
}

// K3: QK^T via MFMA per lower-triangular (h, 64x64 tile); epilogue computes
// hyperbolic dist + causal mask + exp -> P(bf16), pk-packed stores.
__global__ __launch_bounds__(256, 4) void k_qkt_mfma(
        const unsigned short* __restrict__ qh, const unsigned short* __restrict__ kh,
        const float* __restrict__ x2q, const float* __restrict__ y2k,
        const float* __restrict__ c_logits, const float* __restrict__ geo_scale,
        unsigned short* __restrict__ P) {
    const int N = 512;
    int p = blockIdx.x, h = blockIdx.y;
    int qt = 0;
    while ((qt + 1) * (qt + 2) / 2 <= p) qt++;
    int kt = p - qt * (qt + 1) / 2;
    int tid = threadIdx.x, lane = tid & 63, wv = tid >> 6;
    int wr = wv >> 1, wc = wv & 1;
    int l15 = lane & 15, kb = lane >> 4;
    int qrow0 = qt * 64 + wr * 32, kcol0 = kt * 64 + wc * 32;
    const unsigned short* qb = qh + ((size_t)h * N + qrow0 + l15) * 64 + kb * 8;
    const unsigned short* kb_ = kh + ((size_t)h * N + kcol0 + l15) * 64 + kb * 8;
    f32x4 acc[2][2] = {};
    #pragma unroll
    for (int kk = 0; kk < 2; ++kk) {
        s16x8 a0 = *(const s16x8*)(qb + kk * 32);
        s16x8 a1 = *(const s16x8*)(qb + 16 * 64 + kk * 32);
        s16x8 b0 = *(const s16x8*)(kb_ + kk * 32);
        s16x8 b1 = *(const s16x8*)(kb_ + 16 * 64 + kk * 32);
        acc[0][0] = __builtin_amdgcn_mfma_f32_16x16x32_bf16(a0, b0, acc[0][0], 0, 0, 0);
        acc[0][1] = __builtin_amdgcn_mfma_f32_16x16x32_bf16(a0, b1, acc[0][1], 0, 0, 0);
        acc[1][0] = __builtin_amdgcn_mfma_f32_16x16x32_bf16(a1, b0, acc[1][0], 0, 0, 0);
        acc[1][1] = __builtin_amdgcn_mfma_f32_16x16x32_bf16(a1, b1, acc[1][1], 0, 0, 0);
    }
    float c = log1pf(expf(c_logits[h]));
    float sqc = fmaxf(sqrtf(c), EPSF);
    float gs = geo_scale[h];
    #pragma unroll
    for (int mi = 0; mi < 2; ++mi)
        #pragma unroll
        for (int r = 0; r < 4; ++r) {
            int qi = qrow0 + mi * 16 + kb * 4 + r;
            float x2 = x2q[h * N + qi];
            float b_ = 1.f - c * x2;
            float pe[2];
            #pragma unroll
            for (int ni = 0; ni < 2; ++ni) {
                int ki = kcol0 + ni * 16 + l15;
                float y2 = y2k[h * N + ki];
                float dot = acc[mi][ni][r];
                float a_ = 1.f + c * (y2 - 2.f * dot);
                float num2 = a_ * a_ * x2 + b_ * b_ * y2 - 2.f * a_ * b_ * dot;
                float den = fmaxf(1.f - 2.f * c * dot + c * c * x2 * y2, EPSF);
                float nrm = sqrtf(fmaxf(num2, 0.f)) / den;
                if (nrm >= 1.f) nrm = 1.f - EPSF;
                float arg = fminf(sqc * nrm, 1.f - EPSF);
                float s = -gs * (2.f * atanhf(arg) / sqc);
                pe[ni] = (ki <= qi) ? expf(s) : 0.f;
            }
            unsigned pk = cvt_pk_bf16(pe[0], pe[1]);
            unsigned short* prow = P + ((size_t)(h * N + qi)) * N + kcol0 + l15;
            prow[0]  = (unsigned short)(pk & 0xffffu);
            prow[16] = (unsigned short)(pk >> 16);
        }
}

// K4: O = P @ V via MFMA; row-sum via extra MFMA against all-ones B fragment
// (sum lands in the accumulator with exactly the C row-layout the epilogue
// needs -> no shuffles, no LDS, no barrier).
__global__ __launch_bounds__(256, 4) void k_pv_mfma(
        const unsigned short* __restrict__ P, const unsigned short* __restrict__ vt,
        unsigned short* __restrict__ aout) {
    const int N = 512;
    int qt = blockIdx.x, h = blockIdx.y;
    int tid = threadIdx.x, lane = tid & 63, wv = tid >> 6;
    int wr = wv >> 1, wc = wv & 1;
    int l15 = lane & 15, kb = lane >> 4;
    int r0 = qt * 64 + wr * 32;
    int d0 = wc * 32;
    s16x8 ones;
    #pragma unroll
    for (int i = 0; i < 8; ++i) ones[i] = (short)0x3F80;   // bf16 1.0
    const unsigned short* Pb = P + ((size_t)(h * N + r0 + l15)) * N + kb * 8;
    const unsigned short* Vb = vt + ((size_t)(h * 64 + d0 + l15)) * N + kb * 8;
    f32x4 acc[2][2] = {};
    f32x4 acc_s[2] = {};
    int kend = r0 + 32;
    for (int k0 = 0; k0 < kend; k0 += 32) {
        s16x8 a0 = *(const s16x8*)(Pb + k0);
        s16x8 a1 = *(const s16x8*)(Pb + (size_t)16 * N + k0);
        s16x8 b0 = *(const s16x8*)(Vb + k0);
        s16x8 b1 = *(const s16x8*)(Vb + (size_t)16 * N + k0);
        acc[0][0] = __builtin_amdgcn_mfma_f32_16x16x32_bf16(a0, b0, acc[0][0], 0, 0, 0);
        acc[0][1] = __builtin_amdgcn_mfma_f32_16x16x32_bf16(a0, b1, acc[0][1], 0, 0, 0);
        acc[1][0] = __builtin_amdgcn_mfma_f32_16x16x32_bf16(a1, b0, acc[1][0], 0, 0, 0);
        acc[1][1] = __builtin_amdgcn_mfma_f32_16x16x32_bf16(a1, b1, acc[1][1], 0, 0, 0);
        acc_s[0] = __builtin_amdgcn_mfma_f32_16x16x32_bf16(a0, ones, acc_s[0], 0, 0, 0);
        acc_s[1] = __builtin_amdgcn_mfma_f32_16x16x32_bf16(a1, ones, acc_s[1], 0, 0, 0);
    }
    #pragma unroll
    for (int mi = 0; mi < 2; ++mi)
        #pragma unroll
        for (int r = 0; r < 4; ++r) {
            int row_l = wr * 32 + mi * 16 + kb * 4 + r;
            int qi = qt * 64 + row_l;
            float il = 1.f / acc_s[mi][r];
            unsigned pk = cvt_pk_bf16(acc[mi][0][r] * il, acc[mi][1][r] * il);
            unsigned short* orow = aout + (size_t)qi * 512 + h * 64 + d0 + l15;
            orow[0]  = (unsigned short)(pk & 0xffffu);
            orow[16] = (unsigned short)(pk >> 16);
        }
}

// K5: out = aout(bf16) @ W_out + b. B strided-gathered fp32 -> pk-cvt bf16.
__global__ __launch_bounds__(256, 4) void k_out(
        const unsigned short* __restrict__ A, const float* __restrict__ W,
        const float* __restrict__ bias, float* __restrict__ C) {
    const int K = 512, NN = 512;
    int tid = threadIdx.x;
    int wv = tid >> 6, lane = tid & 63, l15 = lane & 15, kb = lane >> 4;
    int wid = blockIdx.x * 4 + wv;
    int wr = wid / 16, wc = wid % 16;
    int col0 = wc * 32;
    const unsigned short* Ab = A + (size_t)(wr * 32 + l15) * K + kb * 8;
    f32x4 acc[2][2] = {};
    #pragma unroll 2
    for (int k0 = 0; k0 < K; k0 += 32) {
        s16x8 a0 = *(const s16x8*)(Ab + k0);
        s16x8 a1 = *(const s16x8*)(Ab + 16 * K + k0);
        float w0[8], w1[8];
        #pragma unroll
        for (int t = 0; t < 8; ++t) {
            const float* wp = W + (size_t)(k0 + kb * 8 + t) * NN + col0 + l15;
            w0[t] = wp[0];
            w1[t] = wp[16];
        }
        s16x8 b0 = pack8(w0);
        s16x8 b1 = pack8(w1);
        acc[0][0] = __builtin_amdgcn_mfma_f32_16x16x32_bf16(a0, b0, acc[0][0], 0, 0, 0);
        acc[0][1] = __builtin_amdgcn_mfma_f32_16x16x32_bf16(a0, b1, acc[0][1], 0, 0, 0);
        acc[1][0] = __builtin_amdgcn_mfma_f32_16x16x32_bf16(a1, b0, acc[1][0], 0, 0, 0);
        acc[1][1] = __builtin_amdgcn_mfma_f32_16x16x32_bf16(a1, b1, acc[1][1], 0, 0, 0);
    }
    #pragma unroll
    for (int mi = 0; mi < 2; ++mi)
        #pragma unroll
        for (int r = 0; r < 4; ++r) {
            int row = wr * 32 + mi * 16 + kb * 4 + r;
            #pragma unroll
            for (int ni = 0; ni < 2; ++ni) {
                int col = col0 + ni * 16 + l15;
                C[(size_t)row * NN + col] = acc[mi][ni][r] + bias[col];
            }
        }
}

extern "C" void kernel_launch(void* const* d_in, const int* in_sizes, int n_in,
                              void* d_out, int out_size, void* d_ws, size_t ws_size,
                              hipStream_t stream) {
    const float* x_hyp     = (const float*)d_in[0];
    const float* freqs     = (const float*)d_in[1];
    const float* c_sphere  = (const float*)d_in[2];
    const float* w_qkv     = (const float*)d_in[3];
    const float* b_qkv     = (const float*)d_in[4];
    const float* w_out     = (const float*)d_in[5];
    const float* b_out     = (const float*)d_in[6];
    const float* c_logits  = (const float*)d_in[7];
    const float* geo_scale = (const float*)d_in[8];
    float* out = (float*)d_out;

    const int N = 512, H = 8;
    char* base = (char*)d_ws;
    float*          qkv    = (float*)base;             base += 3 * 1024 * 1024;
    unsigned short* qh16   = (unsigned short*)base;    base += 512 * 1024;
    unsigned short* kh16   = (unsigned short*)base;    base += 512 * 1024;
    unsigned short* vt16   = (unsigned short*)base;    base += 512 * 1024;
    unsigned short* aout16 = (unsigned short*)base;    base += 512 * 1024;
    float*          x2q    = (float*)base;             base += 16 * 1024;
    float*          y2k    = (float*)base;             base += 16 * 1024;
    unsigned short* P16    = (unsigned short*)base;    base += 4 * 1024 * 1024;

    k_qkv<<<192, 256, 0, stream>>>(x_hyp, w_qkv, b_qkv, c_sphere, qkv);
    k_rope_expmap<<<(H * N) / 4, 256, 0, stream>>>(qkv, freqs, c_logits,
                                                   qh16, kh16, vt16, x2q, y2k);
    k_qkt_mfma<<<dim3(36, H), 256, 0, stream>>>(qh16, kh16, x2q, y2k,
                                                c_logits, geo_scale, P16);
    k_pv_mfma<<<dim3(8, H), 256, 0, stream>>>(P16, vt16, aout16);
    k_out<<<64, 256, 0, stream>>>(aout16, w_out, b_out, out);
}

// Round 9
// 75.544 us; speedup vs baseline: 1.0601x; 1.0349x over previous
//
#include <hip/hip_runtime.h>
#include <math.h>

#define EPSF 1e-7f

typedef __attribute__((ext_vector_type(4))) float f32x4;
typedef __attribute__((ext_vector_type(8))) short s16x8;

__device__ __forceinline__ unsigned short f2bf(float f) {
    unsigned u = __float_as_uint(f);
    u = (u + 0x7fffu + ((u >> 16) & 1u)) >> 16;
    return (unsigned short)u;
}
__device__ __forceinline__ float bf2f(unsigned short s) {
    return __uint_as_float(((unsigned)s) << 16);
}
__device__ __forceinline__ float wave_reduce_sum(float v) {
    #pragma unroll
    for (int o = 32; o > 0; o >>= 1) v += __shfl_xor(v, o, 64);
    return v;
}

// K0: prep. blocks 0..191: W_qkv f32[512][1536] -> WqT bf16[1536][512];
// blocks 192..255: W_out -> WoT bf16[512][512]; blocks 256..263: x norms ->
// sL (logmap row scale) + x -> bf16.
__global__ __launch_bounds__(256, 4) void k_prep(
        const float* __restrict__ W_qkv, const float* __restrict__ W_out,
        const float* __restrict__ x, const float* __restrict__ c_sphere,
        unsigned short* __restrict__ WqT, unsigned short* __restrict__ WoT,
        unsigned short* __restrict__ x16, float* __restrict__ sL_g) {
    int b = blockIdx.x;
    int tid = threadIdx.x;
    if (b < 256) {
        const float* in; unsigned short* out; int N, bx, by;
        if (b < 192) { in = W_qkv; out = WqT; N = 1536; bx = b % 24; by = b / 24; }
        else { int b2 = b - 192; in = W_out; out = WoT; N = 512; bx = b2 % 8; by = b2 / 8; }
        const int K = 512;
        __shared__ float t[64][65];
        int k0 = by * 64, n0 = bx * 64;
        int c = tid & 63, r0 = tid >> 6;
        #pragma unroll
        for (int i = 0; i < 16; ++i) {
            int r = i * 4 + r0;
            t[r][c] = in[(size_t)(k0 + r) * N + n0 + c];
        }
        __syncthreads();
        #pragma unroll
        for (int i = 0; i < 16; ++i) {
            int r = i * 4 + r0;
            out[(size_t)(n0 + r) * K + k0 + c] = f2bf(t[c][r]);
        }
    } else {
        int row0 = (b - 256) * 64;
        __shared__ float part[64][4];
        int row_l = tid >> 2, seg = tid & 3;
        const float* xr = x + (size_t)(row0 + row_l) * 512 + seg * 128;
        float ss = 0.f;
        #pragma unroll
        for (int i = 0; i < 32; ++i) {
            float4 v = *(const float4*)(xr + i * 4);
            ss += v.x * v.x + v.y * v.y + v.z * v.z + v.w * v.w;
        }
        part[row_l][seg] = ss;
        __syncthreads();
        if (tid < 64) {
            float s2 = part[tid][0] + part[tid][1] + part[tid][2] + part[tid][3];
            float c = c_sphere[0];
            float sqc = fmaxf(sqrtf(c), EPSF);
            float yn = sqrtf(s2);
            sL_g[row0 + tid] = (yn < EPSF) ? 0.f
                : atanhf(fminf(yn, 1.f - EPSF)) / (sqc * fmaxf(yn, EPSF));
        }
        for (int idx = tid; idx < 64 * 128; idx += 256) {
            int r = idx >> 7, c4 = (idx & 127) * 4;
            float4 v = *(const float4*)(x + (size_t)(row0 + r) * 512 + c4);
            ushort4 o = make_ushort4(f2bf(v.x), f2bf(v.y), f2bf(v.z), f2bf(v.w));
            *(ushort4*)(x16 + (size_t)(row0 + r) * 512 + c4) = o;
        }
    }
}

// K1: qkv = diag(sL) * (x16 @ WqT^T) + b. Pure contiguous-bf16 MFMA GEMM.
__global__ __launch_bounds__(256, 4) void k_qkv(
        const unsigned short* __restrict__ x16, const unsigned short* __restrict__ WqT,
        const float* __restrict__ bias, const float* __restrict__ sL_g,
        float* __restrict__ qkv) {
    const int K = 512, NN = 1536;
    int tid = threadIdx.x;
    int wv = tid >> 6, lane = tid & 63, l15 = lane & 15, kb = lane >> 4;
    int wid = blockIdx.x * 4 + wv;
    int wr = wid / 48, wc = wid % 48;
    int col0 = wc * 32;
    const unsigned short* Ab = x16 + (size_t)(wr * 32 + l15) * K + kb * 8;
    const unsigned short* Bb = WqT + (size_t)(col0 + l15) * K + kb * 8;
    f32x4 acc[2][2] = {};
    #pragma unroll 4
    for (int k0 = 0; k0 < K; k0 += 32) {
        s16x8 a0 = *(const s16x8*)(Ab + k0);
        s16x8 a1 = *(const s16x8*)(Ab + 16 * K + k0);
        s16x8 b0 = *(const s16x8*)(Bb + k0);
        s16x8 b1 = *(const s16x8*)(Bb + 16 * K + k0);
        acc[0][0] = __builtin_amdgcn_mfma_f32_16x16x32_bf16(a0, b0, acc[0][0], 0, 0, 0);
        acc[0][1] = __builtin_amdgcn_mfma_f32_16x16x32_bf16(a0, b1, acc[0][1], 0, 0, 0);
        acc[1][0] = __builtin_amdgcn_mfma_f32_16x16x32_bf16(a1, b0, acc[1][0], 0, 0, 0);
        acc[1][1] = __builtin_amdgcn_mfma_f32_16x16x32_bf16(a1, b1, acc[1][1], 0, 0, 0);
    }
    #pragma unroll
    for (int mi = 0; mi < 2; ++mi)
        #pragma unroll
        for (int r = 0; r < 4; ++r) {
            int row = wr * 32 + mi * 16 + kb * 4 + r;
            float sc = sL_g[row];
            #pragma unroll
            for (int ni = 0; ni < 2; ++ni) {
                int col = col0 + ni * 16 + l15;
                qkv[(size_t)row * NN + col] = acc[mi][ni][r] * sc + bias[col];
            }
        }
}

// K2: RoPE on q,k; expmap0; relayouts. One wave per (h,n) vector.
__global__ void k_rope_expmap(const float* __restrict__ qkv, const float* __restrict__ freqs,
                              const float* __restrict__ c_logits,
                              unsigned short* __restrict__ qh, unsigned short* __restrict__ kh,
                              unsigned short* __restrict__ vt,
                              float* __restrict__ x2q, float* __restrict__ y2k) {
    const int N = 512;
    int wave = threadIdx.x >> 6, lane = threadIdx.x & 63;
    int vec = blockIdx.x * 4 + wave;     // vec = h*N + n
    int h = vec >> 9;
    int n = vec & 511;
    float c = log1pf(expf(c_logits[h]));
    float sqc = fmaxf(sqrtf(c), EPSF);
    int j = lane & 31;
    float f = freqs[n * 32 + j];
    float cs = cosf(f), sn = sinf(f);
    const float* base = qkv + (size_t)n * 1536;
    size_t oidx = ((size_t)h * N + n) * 64 + lane;
    {
        float qa = base[h * 64 + lane];
        float qb = base[h * 64 + (lane ^ 32)];
        float qr = (lane < 32) ? (qa * cs - qb * sn) : (qa * cs + qb * sn);
        float vn2 = wave_reduce_sum(qr * qr);
        float vn = sqrtf(vn2);
        float scale, fn;
        if (vn < EPSF) { scale = 0.f; fn = 0.f; }
        else {
            float mag = tanhf(sqc * vn) / sqc;
            scale = mag / fmaxf(vn, EPSF);
            fn = mag;
            if (fn >= 1.f) { scale *= (1.f - EPSF) / fn; fn = 1.f - EPSF; }
        }
        qh[oidx] = f2bf(qr * scale);
        if (lane == 0) x2q[h * N + n] = fn * fn;
    }
    {
        float ka = base[512 + h * 64 + lane];
        float kb = base[512 + h * 64 + (lane ^ 32)];
        float kr = (lane < 32) ? (ka * cs - kb * sn) : (ka * cs + kb * sn);
        float vn2 = wave_reduce_sum(kr * kr);
        float vn = sqrtf(vn2);
        float scale, fn;
        if (vn < EPSF) { scale = 0.f; fn = 0.f; }
        else {
            float mag = tanhf(sqc * vn) / sqc;
            scale = mag / fmaxf(vn, EPSF);
            fn = mag;
            if (fn >= 1.f) { scale *= (1.f - EPSF) / fn; fn = 1.f - EPSF; }
        }
        kh[oidx] = f2bf(kr * scale);
        if (lane == 0) y2k[h * N + n] = fn * fn;
    }
    vt[((size_t)h * 64 + lane) * N + n] = f2bf(base[1024 + h * 64 + lane]);
}

// K3: QK^T via MFMA per lower-triangular (h, 64x64 tile); epilogue computes
// hyperbolic dist + causal mask + exp -> P(bf16).
__global__ __launch_bounds__(256, 4) void k_qkt_mfma(
        const unsigned short* __restrict__ qh, const unsigned short* __restrict__ kh,
        const float* __restrict__ x2q, const float* __restrict__ y2k,
        const float* __restrict__ c_logits, const float* __restrict__ geo_scale,
        unsigned short* __restrict__ P) {
    const int N = 512;
    int p = blockIdx.x, h = blockIdx.y;
    int qt = 0;
    while ((qt + 1) * (qt + 2) / 2 <= p) qt++;
    int kt = p - qt * (qt + 1) / 2;
    int tid = threadIdx.x, lane = tid & 63, wv = tid >> 6;
    int wr = wv >> 1, wc = wv & 1;
    int l15 = lane & 15, kb = lane >> 4;
    int qrow0 = qt * 64 + wr * 32, kcol0 = kt * 64 + wc * 32;
    const unsigned short* qb = qh + ((size_t)h * N + qrow0 + l15) * 64 + kb * 8;
    const unsigned short* kb_ = kh + ((size_t)h * N + kcol0 + l15) * 64 + kb * 8;
    f32x4 acc[2][2] = {};
    #pragma unroll
    for (int kk = 0; kk < 2; ++kk) {
        s16x8 a0 = *(const s16x8*)(qb + kk * 32);
        s16x8 a1 = *(const s16x8*)(qb + 16 * 64 + kk * 32);
        s16x8 b0 = *(const s16x8*)(kb_ + kk * 32);
        s16x8 b1 = *(const s16x8*)(kb_ + 16 * 64 + kk * 32);
        acc[0][0] = __builtin_amdgcn_mfma_f32_16x16x32_bf16(a0, b0, acc[0][0], 0, 0, 0);
        acc[0][1] = __builtin_amdgcn_mfma_f32_16x16x32_bf16(a0, b1, acc[0][1], 0, 0, 0);
        acc[1][0] = __builtin_amdgcn_mfma_f32_16x16x32_bf16(a1, b0, acc[1][0], 0, 0, 0);
        acc[1][1] = __builtin_amdgcn_mfma_f32_16x16x32_bf16(a1, b1, acc[1][1], 0, 0, 0);
    }
    float c = log1pf(expf(c_logits[h]));
    float sqc = fmaxf(sqrtf(c), EPSF);
    float gs = geo_scale[h];
    #pragma unroll
    for (int mi = 0; mi < 2; ++mi)
        #pragma unroll
        for (int r = 0; r < 4; ++r) {
            int qi = qrow0 + mi * 16 + kb * 4 + r;
            float x2 = x2q[h * N + qi];
            float b_ = 1.f - c * x2;
            #pragma unroll
            for (int ni = 0; ni < 2; ++ni) {
                int ki = kcol0 + ni * 16 + l15;
                float y2 = y2k[h * N + ki];
                float dot = acc[mi][ni][r];
                float a_ = 1.f + c * (y2 - 2.f * dot);
                float num2 = a_ * a_ * x2 + b_ * b_ * y2 - 2.f * a_ * b_ * dot;
                float den = fmaxf(1.f - 2.f * c * dot + c * c * x2 * y2, EPSF);
                float nrm = sqrtf(fmaxf(num2, 0.f)) / den;
                if (nrm >= 1.f) nrm = 1.f - EPSF;
                float arg = fminf(sqc * nrm, 1.f - EPSF);
                float s = -gs * (2.f * atanhf(arg) / sqc);
                float pe = (ki <= qi) ? expf(s) : 0.f;
                P[((size_t)(h * N + qi)) * N + ki] = f2bf(pe);
            }
        }
}

// K4: O = P @ V via MFMA; row-sum via extra MFMA against all-ones B fragment
// (denominator lands in the accumulator with exactly the C row-layout the
// epilogue needs -> no shuffles, no LDS, no barrier).
__global__ __launch_bounds__(256, 4) void k_pv_mfma(
        const unsigned short* __restrict__ P, const unsigned short* __restrict__ vt,
        unsigned short* __restrict__ aout) {
    const int N = 512;
    int qt = blockIdx.x, h = blockIdx.y;
    int tid = threadIdx.x, lane = tid & 63, wv = tid >> 6;
    int wr = wv >> 1, wc = wv & 1;
    int l15 = lane & 15, kb = lane >> 4;
    int r0 = qt * 64 + wr * 32;
    int d0 = wc * 32;
    s16x8 ones;
    #pragma unroll
    for (int i = 0; i < 8; ++i) ones[i] = (short)0x3F80;   // bf16 1.0
    const unsigned short* Pb = P + ((size_t)(h * N + r0 + l15)) * N + kb * 8;
    const unsigned short* Vb = vt + ((size_t)(h * 64 + d0 + l15)) * N + kb * 8;
    f32x4 acc[2][2] = {};
    f32x4 acc_s[2] = {};
    int kend = r0 + 32;
    for (int k0 = 0; k0 < kend; k0 += 32) {
        s16x8 a0 = *(const s16x8*)(Pb + k0);
        s16x8 a1 = *(const s16x8*)(Pb + (size_t)16 * N + k0);
        s16x8 b0 = *(const s16x8*)(Vb + k0);
        s16x8 b1 = *(const s16x8*)(Vb + (size_t)16 * N + k0);
        acc[0][0] = __builtin_amdgcn_mfma_f32_16x16x32_bf16(a0, b0, acc[0][0], 0, 0, 0);
        acc[0][1] = __builtin_amdgcn_mfma_f32_16x16x32_bf16(a0, b1, acc[0][1], 0, 0, 0);
        acc[1][0] = __builtin_amdgcn_mfma_f32_16x16x32_bf16(a1, b0, acc[1][0], 0, 0, 0);
        acc[1][1] = __builtin_amdgcn_mfma_f32_16x16x32_bf16(a1, b1, acc[1][1], 0, 0, 0);
        acc_s[0] = __builtin_amdgcn_mfma_f32_16x16x32_bf16(a0, ones, acc_s[0], 0, 0, 0);
        acc_s[1] = __builtin_amdgcn_mfma_f32_16x16x32_bf16(a1, ones, acc_s[1], 0, 0, 0);
    }
    #pragma unroll
    for (int mi = 0; mi < 2; ++mi)
        #pragma unroll
        for (int r = 0; r < 4; ++r) {
            int row_l = wr * 32 + mi * 16 + kb * 4 + r;
            int qi = qt * 64 + row_l;
            float il = 1.f / acc_s[mi][r];
            #pragma unroll
            for (int ni = 0; ni < 2; ++ni) {
                int d = d0 + ni * 16 + l15;
                aout[(size_t)qi * 512 + h * 64 + d] = f2bf(acc[mi][ni][r] * il);
            }
        }
}

// K5: out = aout(bf16) @ WoT(bf16)^T + b. Clean contiguous fragments.
__global__ __launch_bounds__(256, 4) void k_out(
        const unsigned short* __restrict__ A, const unsigned short* __restrict__ Bt,
        const float* __restrict__ bias, float* __restrict__ C) {
    const int K = 512, NN = 512;
    int tid = threadIdx.x;
    int wv = tid >> 6, lane = tid & 63, l15 = lane & 15, kb = lane >> 4;
    int wid = blockIdx.x * 4 + wv;
    int wr = wid / 16, wc = wid % 16;
    int col0 = wc * 32;
    const unsigned short* Ab = A + (size_t)(wr * 32 + l15) * K + kb * 8;
    const unsigned short* Bb = Bt + (size_t)(col0 + l15) * K + kb * 8;
    f32x4 acc[2][2] = {};
    #pragma unroll 4
    for (int k0 = 0; k0 < K; k0 += 32) {
        s16x8 a0 = *(const s16x8*)(Ab + k0);
        s16x8 a1 = *(const s16x8*)(Ab + 16 * K + k0);
        s16x8 b0 = *(const s16x8*)(Bb + k0);
        s16x8 b1 = *(const s16x8*)(Bb + 16 * K + k0);
        acc[0][0] = __builtin_amdgcn_mfma_f32_16x16x32_bf16(a0, b0, acc[0][0], 0, 0, 0);
        acc[0][1] = __builtin_amdgcn_mfma_f32_16x16x32_bf16(a0, b1, acc[0][1], 0, 0, 0);
        acc[1][0] = __builtin_amdgcn_mfma_f32_16x16x32_bf16(a1, b0, acc[1][0], 0, 0, 0);
        acc[1][1] = __builtin_amdgcn_mfma_f32_16x16x32_bf16(a1, b1, acc[1][1], 0, 0, 0);
    }
    #pragma unroll
    for (int mi = 0; mi < 2; ++mi)
        #pragma unroll
        for (int r = 0; r < 4; ++r) {
            int row = wr * 32 + mi * 16 + kb * 4 + r;
            #pragma unroll
            for (int ni = 0; ni < 2; ++ni) {
                int col = col0 + ni * 16 + l15;
                C[(size_t)row * NN + col] = acc[mi][ni][r] + bias[col];
            }
        }
}

extern "C" void kernel_launch(void* const* d_in, const int* in_sizes, int n_in,
                              void* d_out, int out_size, void* d_ws, size_t ws_size,
                              hipStream_t stream) {
    const float* x_hyp     = (const float*)d_in[0];
    const float* freqs     = (const float*)d_in[1];
    const float* c_sphere  = (const float*)d_in[2];
    const float* w_qkv     = (const float*)d_in[3];
    const float* b_qkv     = (const float*)d_in[4];
    const float* w_out     = (const float*)d_in[5];
    const float* b_out     = (const float*)d_in[6];
    const float* c_logits  = (const float*)d_in[7];
    const float* geo_scale = (const float*)d_in[8];
    float* out = (float*)d_out;

    const int N = 512, H = 8;
    char* base = (char*)d_ws;
    unsigned short* WqT    = (unsigned short*)base;    base += 1536 * 512 * 2;
    unsigned short* WoT    = (unsigned short*)base;    base += 512 * 512 * 2;
    unsigned short* x16    = (unsigned short*)base;    base += 512 * 512 * 2;
    float*          sL_g   = (float*)base;             base += 4 * 1024;
    float*          qkv    = (float*)base;             base += 3 * 1024 * 1024;
    unsigned short* qh16   = (unsigned short*)base;    base += 512 * 1024;
    unsigned short* kh16   = (unsigned short*)base;    base += 512 * 1024;
    unsigned short* vt16   = (unsigned short*)base;    base += 512 * 1024;
    unsigned short* aout16 = (unsigned short*)base;    base += 512 * 1024;
    float*          x2q    = (float*)base;             base += 16 * 1024;
    float*          y2k    = (float*)base;             base += 16 * 1024;
    unsigned short* P16    = (unsigned short*)base;    base += 4 * 1024 * 1024;

    k_prep<<<264, 256, 0, stream>>>(w_qkv, w_out, x_hyp, c_sphere, WqT, WoT, x16, sL_g);
    k_qkv<<<192, 256, 0, stream>>>(x16, WqT, b_qkv, sL_g, qkv);
    k_rope_expmap<<<(H * N) / 4, 256, 0, stream>>>(qkv, freqs, c_logits,
                                                   qh16, kh16, vt16, x2q, y2k);
    k_qkt_mfma<<<dim3(36, H), 256, 0, stream>>>(qh16, kh16, x2q, y2k,
                                                c_logits, geo_scale, P16);
    k_pv_mfma<<<dim3(8, H), 256, 0, stream>>>(P16, vt16, aout16);
    k_out<<<64, 256, 0, stream>>>(aout16, WoT, b_out, out);
}

// Round 10
// 64.338 us; speedup vs baseline: 1.2447x; 1.1742x over previous
//
#include <hip/hip_runtime.h>
#include <math.h>

#define EPSF 1e-7f

typedef __attribute__((ext_vector_type(4))) float f32x4;
typedef __attribute__((ext_vector_type(8))) short s16x8;

__device__ __forceinline__ unsigned short f2bf(float f) {
    unsigned u = __float_as_uint(f);
    u = (u + 0x7fffu + ((u >> 16) & 1u)) >> 16;
    return (unsigned short)u;
}
__device__ __forceinline__ s16x8 cvt8(const float* p) {
    s16x8 r;
    #pragma unroll
    for (int i = 0; i < 8; ++i) r[i] = (short)f2bf(p[i]);
    return r;
}
__device__ __forceinline__ float wave_reduce_sum(float v) {
    #pragma unroll
    for (int o = 32; o > 0; o >>= 1) v += __shfl_xor(v, o, 64);
    return v;
}

// K1: qkv = diag(s_logmap) * (x @ W_qkv) + b.  16x16 MFMA tiles, one per wave:
// 3072 waves (vs 768 at 32x32) to hide VMEM latency. A = x fp32 cvt in-reg,
// B = W fp32 [K][N] strided-gathered + cvt. 16-row logmap prologue per block.
__global__ __launch_bounds__(256, 4) void k_qkv(
        const float* __restrict__ x, const float* __restrict__ W,
        const float* __restrict__ bias, const float* __restrict__ c_sphere,
        float* __restrict__ qkv) {
    const int K = 512, NN = 1536;
    __shared__ float part[16][16];
    __shared__ float sL[16];
    int tid = threadIdx.x;
    int wr = blockIdx.x / 24;          // 16-row tile, same for all 4 waves
    int cg = blockIdx.x % 24;          // group of 4 col-tiles of 16
    {   // prologue: ||x_row||^2 for the block's 16 rows (16 thr/row x 32 elems)
        int row = tid >> 4, seg = tid & 15;
        const float* xr = x + (size_t)(wr * 16 + row) * K + seg * 32;
        float ss = 0.f;
        #pragma unroll
        for (int i = 0; i < 8; ++i) {
            float4 v = *(const float4*)(xr + i * 4);
            ss += v.x * v.x + v.y * v.y + v.z * v.z + v.w * v.w;
        }
        part[row][seg] = ss;
    }
    __syncthreads();
    if (tid < 16) {
        float ss = 0.f;
        #pragma unroll
        for (int i = 0; i < 16; ++i) ss += part[tid][i];
        float c = c_sphere[0];
        float sqc = fmaxf(sqrtf(c), EPSF);
        float yn = sqrtf(ss);
        sL[tid] = (yn < EPSF) ? 0.f
                 : atanhf(fminf(yn, 1.f - EPSF)) / (sqc * fmaxf(yn, EPSF));
    }
    __syncthreads();
    int wv = tid >> 6, lane = tid & 63, l15 = lane & 15, kb = lane >> 4;
    int col0 = cg * 64 + wv * 16;
    const float* Ab = x + (size_t)(wr * 16 + l15) * K + kb * 8;
    f32x4 acc = {};
    #pragma unroll 4
    for (int k0 = 0; k0 < K; k0 += 32) {
        s16x8 a = cvt8(Ab + k0);
        s16x8 b;
        #pragma unroll
        for (int t = 0; t < 8; ++t)
            b[t] = (short)f2bf(W[(size_t)(k0 + kb * 8 + t) * NN + col0 + l15]);
        acc = __builtin_amdgcn_mfma_f32_16x16x32_bf16(a, b, acc, 0, 0, 0);
    }
    int col = col0 + l15;
    float bv = bias[col];
    #pragma unroll
    for (int r = 0; r < 4; ++r) {
        int row_l = kb * 4 + r;
        qkv[(size_t)(wr * 16 + row_l) * NN + col] = acc[r] * sL[row_l] + bv;
    }
}

// K2: RoPE on q,k; expmap0; relayouts. One wave per (h,n) vector.
__global__ void k_rope_expmap(const float* __restrict__ qkv, const float* __restrict__ freqs,
                              const float* __restrict__ c_logits,
                              unsigned short* __restrict__ qh, unsigned short* __restrict__ kh,
                              unsigned short* __restrict__ vt,
                              float* __restrict__ x2q, float* __restrict__ y2k) {
    const int N = 512;
    int wave = threadIdx.x >> 6, lane = threadIdx.x & 63;
    int vec = blockIdx.x * 4 + wave;     // vec = h*N + n
    int h = vec >> 9;
    int n = vec & 511;
    float c = log1pf(expf(c_logits[h]));
    float sqc = fmaxf(sqrtf(c), EPSF);
    int j = lane & 31;
    float f = freqs[n * 32 + j];
    float cs = cosf(f), sn = sinf(f);
    const float* base = qkv + (size_t)n * 1536;
    size_t oidx = ((size_t)h * N + n) * 64 + lane;
    {
        float qa = base[h * 64 + lane];
        float qb = base[h * 64 + (lane ^ 32)];
        float qr = (lane < 32) ? (qa * cs - qb * sn) : (qa * cs + qb * sn);
        float vn2 = wave_reduce_sum(qr * qr);
        float vn = sqrtf(vn2);
        float scale, fn;
        if (vn < EPSF) { scale = 0.f; fn = 0.f; }
        else {
            float mag = tanhf(sqc * vn) / sqc;
            scale = mag / fmaxf(vn, EPSF);
            fn = mag;
            if (fn >= 1.f) { scale *= (1.f - EPSF) / fn; fn = 1.f - EPSF; }
        }
        qh[oidx] = f2bf(qr * scale);
        if (lane == 0) x2q[h * N + n] = fn * fn;
    }
    {
        float ka = base[512 + h * 64 + lane];
        float kb = base[512 + h * 64 + (lane ^ 32)];
        float kr = (lane < 32) ? (ka * cs - kb * sn) : (ka * cs + kb * sn);
        float vn2 = wave_reduce_sum(kr * kr);
        float vn = sqrtf(vn2);
        float scale, fn;
        if (vn < EPSF) { scale = 0.f; fn = 0.f; }
        else {
            float mag = tanhf(sqc * vn) / sqc;
            scale = mag / fmaxf(vn, EPSF);
            fn = mag;
            if (fn >= 1.f) { scale *= (1.f - EPSF) / fn; fn = 1.f - EPSF; }
        }
        kh[oidx] = f2bf(kr * scale);
        if (lane == 0) y2k[h * N + n] = fn * fn;
    }
    vt[((size_t)h * 64 + lane) * N + n] = f2bf(base[1024 + h * 64 + lane]);
}

// K3: QK^T via MFMA per lower-triangular (h, 64x64 tile); epilogue computes
// hyperbolic dist + causal mask + exp -> P(bf16). 288 blocks.
__global__ __launch_bounds__(256, 4) void k_qkt_mfma(
        const unsigned short* __restrict__ qh, const unsigned short* __restrict__ kh,
        const float* __restrict__ x2q, const float* __restrict__ y2k,
        const float* __restrict__ c_logits, const float* __restrict__ geo_scale,
        unsigned short* __restrict__ P) {
    const int N = 512;
    int p = blockIdx.x, h = blockIdx.y;
    int qt = 0;
    while ((qt + 1) * (qt + 2) / 2 <= p) qt++;
    int kt = p - qt * (qt + 1) / 2;
    int tid = threadIdx.x, lane = tid & 63, wv = tid >> 6;
    int wr = wv >> 1, wc = wv & 1;
    int l15 = lane & 15, kb = lane >> 4;
    int qrow0 = qt * 64 + wr * 32, kcol0 = kt * 64 + wc * 32;
    const unsigned short* qb = qh + ((size_t)h * N + qrow0 + l15) * 64 + kb * 8;
    const unsigned short* kb_ = kh + ((size_t)h * N + kcol0 + l15) * 64 + kb * 8;
    f32x4 acc[2][2] = {};
    #pragma unroll
    for (int kk = 0; kk < 2; ++kk) {
        s16x8 a0 = *(const s16x8*)(qb + kk * 32);
        s16x8 a1 = *(const s16x8*)(qb + 16 * 64 + kk * 32);
        s16x8 b0 = *(const s16x8*)(kb_ + kk * 32);
        s16x8 b1 = *(const s16x8*)(kb_ + 16 * 64 + kk * 32);
        acc[0][0] = __builtin_amdgcn_mfma_f32_16x16x32_bf16(a0, b0, acc[0][0], 0, 0, 0);
        acc[0][1] = __builtin_amdgcn_mfma_f32_16x16x32_bf16(a0, b1, acc[0][1], 0, 0, 0);
        acc[1][0] = __builtin_amdgcn_mfma_f32_16x16x32_bf16(a1, b0, acc[1][0], 0, 0, 0);
        acc[1][1] = __builtin_amdgcn_mfma_f32_16x16x32_bf16(a1, b1, acc[1][1], 0, 0, 0);
    }
    float c = log1pf(expf(c_logits[h]));
    float sqc = fmaxf(sqrtf(c), EPSF);
    float gs = geo_scale[h];
    #pragma unroll
    for (int mi = 0; mi < 2; ++mi)
        #pragma unroll
        for (int r = 0; r < 4; ++r) {
            int qi = qrow0 + mi * 16 + kb * 4 + r;
            float x2 = x2q[h * N + qi];
            float b_ = 1.f - c * x2;
            #pragma unroll
            for (int ni = 0; ni < 2; ++ni) {
                int ki = kcol0 + ni * 16 + l15;
                float y2 = y2k[h * N + ki];
                float dot = acc[mi][ni][r];
                float a_ = 1.f + c * (y2 - 2.f * dot);
                float num2 = a_ * a_ * x2 + b_ * b_ * y2 - 2.f * a_ * b_ * dot;
                float den = fmaxf(1.f - 2.f * c * dot + c * c * x2 * y2, EPSF);
                float nrm = sqrtf(fmaxf(num2, 0.f)) / den;
                if (nrm >= 1.f) nrm = 1.f - EPSF;
                float arg = fminf(sqc * nrm, 1.f - EPSF);
                float s = -gs * (2.f * atanhf(arg) / sqc);
                float pe = (ki <= qi) ? expf(s) : 0.f;
                P[((size_t)(h * N + qi)) * N + ki] = f2bf(pe);
            }
        }
}

// K4: O = P @ V via MFMA, 16x16 tiles (1024 waves). Row-sum via extra MFMA
// against all-ones B fragment -> denominator lands in C row-layout directly.
// Grid (32 row-tiles, 8 heads); wave wv -> d-tile wv*16.
__global__ __launch_bounds__(256, 4) void k_pv_mfma(
        const unsigned short* __restrict__ P, const unsigned short* __restrict__ vt,
        unsigned short* __restrict__ aout) {
    const int N = 512;
    int rt = blockIdx.x, h = blockIdx.y;
    int tid = threadIdx.x, lane = tid & 63, wv = tid >> 6;
    int l15 = lane & 15, kb = lane >> 4;
    int r0 = rt * 16;
    int d0 = wv * 16;
    s16x8 ones;
    #pragma unroll
    for (int i = 0; i < 8; ++i) ones[i] = (short)0x3F80;   // bf16 1.0
    const unsigned short* Pb = P + ((size_t)(h * N + r0 + l15)) * N + kb * 8;
    const unsigned short* Vb = vt + ((size_t)(h * 64 + d0 + l15)) * N + kb * 8;
    f32x4 acc = {};
    f32x4 acc_s = {};
    int kend = r0 + 16;                 // causal coverage for rows r0..r0+15
    for (int k0 = 0; k0 < kend; k0 += 32) {
        s16x8 a = *(const s16x8*)(Pb + k0);
        s16x8 b = *(const s16x8*)(Vb + k0);
        acc = __builtin_amdgcn_mfma_f32_16x16x32_bf16(a, b, acc, 0, 0, 0);
        acc_s = __builtin_amdgcn_mfma_f32_16x16x32_bf16(a, ones, acc_s, 0, 0, 0);
    }
    #pragma unroll
    for (int r = 0; r < 4; ++r) {
        int qi = r0 + kb * 4 + r;
        float il = 1.f / acc_s[r];
        aout[(size_t)qi * 512 + h * 64 + d0 + l15] = f2bf(acc[r] * il);
    }
}

// K5: out = aout(bf16) @ W_out + b. 16x16 tiles (1024 waves), W gathered
// fp32->bf16 in-loop.
__global__ __launch_bounds__(256, 4) void k_out(
        const unsigned short* __restrict__ A, const float* __restrict__ W,
        const float* __restrict__ bias, float* __restrict__ C) {
    const int K = 512, NN = 512;
    int tid = threadIdx.x;
    int wv = tid >> 6, lane = tid & 63, l15 = lane & 15, kb = lane >> 4;
    int wr = blockIdx.x / 8;           // 16-row tile
    int cg = blockIdx.x % 8;           // group of 4 col-tiles
    int col0 = cg * 64 + wv * 16;
    const unsigned short* Ab = A + (size_t)(wr * 16 + l15) * K + kb * 8;
    f32x4 acc = {};
    #pragma unroll 4
    for (int k0 = 0; k0 < K; k0 += 32) {
        s16x8 a = *(const s16x8*)(Ab + k0);
        s16x8 b;
        #pragma unroll
        for (int t = 0; t < 8; ++t)
            b[t] = (short)f2bf(W[(size_t)(k0 + kb * 8 + t) * NN + col0 + l15]);
        acc = __builtin_amdgcn_mfma_f32_16x16x32_bf16(a, b, acc, 0, 0, 0);
    }
    int col = col0 + l15;
    float bv = bias[col];
    #pragma unroll
    for (int r = 0; r < 4; ++r)
        C[(size_t)(wr * 16 + kb * 4 + r) * NN + col] = acc[r] + bv;
}

extern "C" void kernel_launch(void* const* d_in, const int* in_sizes, int n_in,
                              void* d_out, int out_size, void* d_ws, size_t ws_size,
                              hipStream_t stream) {
    const float* x_hyp     = (const float*)d_in[0];
    const float* freqs     = (const float*)d_in[1];
    const float* c_sphere  = (const float*)d_in[2];
    const float* w_qkv     = (const float*)d_in[3];
    const float* b_qkv     = (const float*)d_in[4];
    const float* w_out     = (const float*)d_in[5];
    const float* b_out     = (const float*)d_in[6];
    const float* c_logits  = (const float*)d_in[7];
    const float* geo_scale = (const float*)d_in[8];
    float* out = (float*)d_out;

    const int N = 512, H = 8;
    char* base = (char*)d_ws;
    float*          qkv    = (float*)base;             base += 3 * 1024 * 1024;
    unsigned short* qh16   = (unsigned short*)base;    base += 512 * 1024;
    unsigned short* kh16   = (unsigned short*)base;    base += 512 * 1024;
    unsigned short* vt16   = (unsigned short*)base;    base += 512 * 1024;
    unsigned short* aout16 = (unsigned short*)base;    base += 512 * 1024;
    float*          x2q    = (float*)base;             base += 16 * 1024;
    float*          y2k    = (float*)base;             base += 16 * 1024;
    unsigned short* P16    = (unsigned short*)base;    base += 4 * 1024 * 1024;

    k_qkv<<<768, 256, 0, stream>>>(x_hyp, w_qkv, b_qkv, c_sphere, qkv);
    k_rope_expmap<<<(H * N) / 4, 256, 0, stream>>>(qkv, freqs, c_logits,
                                                   qh16, kh16, vt16, x2q, y2k);
    k_qkt_mfma<<<dim3(36, H), 256, 0, stream>>>(qh16, kh16, x2q, y2k,
                                                c_logits, geo_scale, P16);
    k_pv_mfma<<<dim3(32, H), 256, 0, stream>>>(P16, vt16, aout16);
    k_out<<<256, 256, 0, stream>>>(aout16, w_out, b_out, out);
}